// Round 1
// baseline (457.512 us; speedup 1.0000x reference)
//
#include <hip/hip_runtime.h>

// Problem constants (fixed by setup_inputs)
constexpr int NB = 4;
constexpr int NI = 512;
constexpr int NK = 512;
constexpr int NC = 64;
constexpr float LN_EPS = 1e-5f;

constexpr int IC = 32;          // i-chunks per batch in k_S (partial-sum slabs)
constexpr int ILEN = NI / IC;   // 16 i's per chunk

// ---------------------------------------------------------------------------
// k_S: Spart[ic][k,c] = sum_{i in chunk ic} exp(z[b,i,k,c]) * (zmask[b,i,k]+1e-6)
// Per-batch. grid = (K/16)*IC = 1024 blocks, block = 256 (16 k x 16 float4-of-c).
// No atomics, no memset: k_R folds the 32-way partial reduction.
// ---------------------------------------------------------------------------
__global__ __launch_bounds__(256) void k_S(const float* __restrict__ z,
                                           const float* __restrict__ zmask,
                                           float* __restrict__ Spart, int b) {
    int idx = blockIdx.x;
    int ic = idx & (IC - 1);        // 0..31
    int kt = idx >> 5;              // 0..31
    int tid = threadIdx.x;
    int kk = tid >> 4;              // 0..15
    int c4 = tid & 15;              // 0..15
    int k = kt * 16 + kk;

    float4 acc = make_float4(0.f, 0.f, 0.f, 0.f);
#pragma unroll 4
    for (int ii = 0; ii < ILEN; ++ii) {
        int i = ic * ILEN + ii;
        size_t row = ((size_t)(b * NI + i) * NK + k) * NC;
        const float4 zv = *(const float4*)(z + row + c4 * 4);
        float m = zmask[(size_t)(b * NI + i) * NK + k] + 1e-6f;
        acc.x += __expf(zv.x) * m;
        acc.y += __expf(zv.y) * m;
        acc.z += __expf(zv.z) * m;
        acc.w += __expf(zv.w) * m;
    }
    *(float4*)(Spart + (size_t)ic * (NK * NC) + (size_t)k * NC + c4 * 4) = acc;
}

// ---------------------------------------------------------------------------
// k_R: R[b,k,c] = (dot(Q[b,k,:], W1[c,:]) + b1[c]) / sum_ic Spart[ic][k,c]
// Per-batch. grid = K blocks of 64 threads (one per c).
// ---------------------------------------------------------------------------
__global__ __launch_bounds__(64) void k_R(const float* __restrict__ Q,
                                          const float* __restrict__ W1,
                                          const float* __restrict__ b1,
                                          const float* __restrict__ Spart,
                                          float* __restrict__ R, int b) {
    int k = blockIdx.x;
    int c = threadIdx.x;
    __shared__ float q[NC];
    q[c] = Q[((size_t)(b * NK) + k) * NC + c];
    __syncthreads();
    const float* w = W1 + c * NC;
    float acc = b1[c];
#pragma unroll
    for (int j = 0; j < NC; ++j) acc += q[j] * w[j];
    float s = 0.f;
#pragma unroll
    for (int ic = 0; ic < IC; ++ic)
        s += Spart[(size_t)ic * (NK * NC) + (size_t)k * NC + c];
    R[((size_t)(b * NK) + k) * NC + c] = acc / s;
}

// ---------------------------------------------------------------------------
// k_Va: Va[b,i,c] = sum_k mask*(mask+1e-6)*exp(z[b,i,k,c]) * R[b,k,c]
// Per-batch. grid = I blocks, block = 256 (16 k-stripes x 16 float4-of-c).
// z[b] (64 MiB) is L3-resident from k_S(b) two dispatches earlier.
// Also emits per-(b,i) partial (sum, sumsq) for LN1.
// ---------------------------------------------------------------------------
__global__ __launch_bounds__(256) void k_Va(const float* __restrict__ z,
                                            const float* __restrict__ zmask,
                                            const float* __restrict__ R,
                                            float* __restrict__ Va,
                                            float* __restrict__ part1, int b) {
    int i = blockIdx.x;
    int bi = b * NI + i;
    int tid = threadIdx.x;
    int kk = tid >> 4;
    int c4 = tid & 15;

    const float* zrow = z + (size_t)bi * NK * NC;
    const float* mrow = zmask + (size_t)bi * NK;
    const float* Rb = R + (size_t)b * NK * NC;

    float4 acc = make_float4(0.f, 0.f, 0.f, 0.f);
#pragma unroll 2
    for (int kb = 0; kb < NK / 16; ++kb) {
        int k = kb * 16 + kk;
        const float4 zv = *(const float4*)(zrow + (size_t)k * NC + c4 * 4);
        const float4 rv = *(const float4*)(Rb + (size_t)k * NC + c4 * 4);
        float zm = mrow[k];
        float m2 = zm * (zm + 1e-6f);
        acc.x += __expf(zv.x) * m2 * rv.x;
        acc.y += __expf(zv.y) * m2 * rv.y;
        acc.z += __expf(zv.z) * m2 * rv.z;
        acc.w += __expf(zv.w) * m2 * rv.w;
    }

    __shared__ float4 part[256];
    part[tid] = acc;
    __syncthreads();
    // reduce across the 16 kk-stripes (tid = kk*16 + c4)
    for (int s = 128; s >= 16; s >>= 1) {
        if (tid < s) {
            float4 o = part[tid + s];
            float4 m = part[tid];
            m.x += o.x; m.y += o.y; m.z += o.z; m.w += o.w;
            part[tid] = m;
        }
        __syncthreads();
    }
    __shared__ float red[32];
    if (tid < 16) {
        float4 v = part[tid];
        *(float4*)(Va + (size_t)bi * NC + tid * 4) = v;
        red[tid]      = v.x + v.y + v.z + v.w;
        red[16 + tid] = v.x * v.x + v.y * v.y + v.z * v.z + v.w * v.w;
    }
    __syncthreads();
    if (tid == 0) {
        float s0 = 0.f, s1 = 0.f;
        for (int t = 0; t < 16; ++t) { s0 += red[t]; s1 += red[16 + t]; }
        part1[bi * 2]     = s0;
        part1[bi * 2 + 1] = s1;
    }
}

// ---------------------------------------------------------------------------
// k_red: per-batch reduce of (sum, sumsq) partials -> stats[b*2], stats[b*2+1]
// grid = B, block = 256
// ---------------------------------------------------------------------------
__global__ __launch_bounds__(256) void k_red(const float* __restrict__ part,
                                             float* __restrict__ stats) {
    int b = blockIdx.x;
    int tid = threadIdx.x;
    float s0 = 0.f, s1 = 0.f;
    for (int i = tid; i < NI; i += 256) {
        int bi = b * NI + i;
        s0 += part[bi * 2];
        s1 += part[bi * 2 + 1];
    }
    __shared__ float l0[256], l1[256];
    l0[tid] = s0; l1[tid] = s1;
    __syncthreads();
    for (int s = 128; s; s >>= 1) {
        if (tid < s) { l0[tid] += l0[tid + s]; l1[tid] += l1[tid + s]; }
        __syncthreads();
    }
    if (tid == 0) { stats[b * 2] = l0[0]; stats[b * 2 + 1] = l1[0]; }
}

// ---------------------------------------------------------------------------
// k_Y: Y[b,i,c] = V + (LN1(Va) @ W2^T + b2); emits LN2 partials per (b,i)
// grid = B*I, block = 64 (one wave)
// ---------------------------------------------------------------------------
__global__ __launch_bounds__(64) void k_Y(const float* __restrict__ V,
                                          const float* __restrict__ W2,
                                          const float* __restrict__ b2,
                                          const float* __restrict__ Va,
                                          const float* __restrict__ stats1,
                                          float* __restrict__ Y,
                                          float* __restrict__ part2) {
    int bi = blockIdx.x;
    int b = bi >> 9;
    int c = threadIdx.x;
    const float n = (float)(NI * NC);
    float mu = stats1[b * 2] / n;
    float var = stats1[b * 2 + 1] / n - mu * mu;
    float rstd = rsqrtf(var + LN_EPS);

    __shared__ float xn[NC];
    xn[c] = (Va[(size_t)bi * NC + c] - mu) * rstd;
    __syncthreads();

    const float* w = W2 + c * NC;
    float acc = b2[c];
#pragma unroll
    for (int j = 0; j < NC; ++j) acc += xn[j] * w[j];
    float y = V[(size_t)bi * NC + c] + acc;
    Y[(size_t)bi * NC + c] = y;

    float s0 = y, s1 = y * y;
    for (int off = 32; off; off >>= 1) {
        s0 += __shfl_down(s0, off);
        s1 += __shfl_down(s1, off);
    }
    if (c == 0) { part2[bi * 2] = s0; part2[bi * 2 + 1] = s1; }
}

// ---------------------------------------------------------------------------
// k_out: out = LN2(Y), elementwise with per-b stats
// ---------------------------------------------------------------------------
__global__ __launch_bounds__(256) void k_out(const float* __restrict__ Y,
                                             const float* __restrict__ stats2,
                                             float* __restrict__ out) {
    int idx = blockIdx.x * 256 + threadIdx.x;
    int b = idx >> 15;               // / (NI*NC)
    const float n = (float)(NI * NC);
    float mu = stats2[b * 2] / n;
    float var = stats2[b * 2 + 1] / n - mu * mu;
    float rstd = rsqrtf(var + LN_EPS);
    out[idx] = (Y[idx] - mu) * rstd;
}

// ---------------------------------------------------------------------------
extern "C" void kernel_launch(void* const* d_in, const int* in_sizes, int n_in,
                              void* d_out, int out_size, void* d_ws, size_t ws_size,
                              hipStream_t stream) {
    const float* V  = (const float*)d_in[0];
    const float* Q  = (const float*)d_in[1];
    const float* z  = (const float*)d_in[2];
    const float* zm = (const float*)d_in[3];
    const float* W1 = (const float*)d_in[4];
    const float* b1 = (const float*)d_in[5];
    const float* W2 = (const float*)d_in[6];
    const float* b2 = (const float*)d_in[7];
    // d_in[8] is dim == 1 (fixed by setup_inputs)

    float* ws     = (float*)d_ws;
    float* Spart  = ws;                          // IC*NK*NC = 1,048,576 (reused per b)
    float* R      = ws + 1048576;                // 131072
    float* Va     = ws + 1179648;                // 131072
    float* Y      = ws + 1310720;                // 131072
    float* part1  = ws + 1441792;                // 4096
    float* part2  = ws + 1445888;                // 4096
    float* stats1 = ws + 1449984;                // 8
    float* stats2 = ws + 1449992;                // 8

    // Per-batch pipeline: k_Va(b) re-reads z[b] (64 MiB) while it is still
    // L3-resident from k_S(b). Single stream serializes, so Spart reuse is safe.
    for (int b = 0; b < NB; ++b) {
        k_S <<<(NK / 16) * IC, 256, 0, stream>>>(z, zm, Spart, b);
        k_R <<<NK,             64,  0, stream>>>(Q, W1, b1, Spart, R, b);
        k_Va<<<NI,             256, 0, stream>>>(z, zm, R, Va, part1, b);
    }
    k_red<<<NB,                 256, 0, stream>>>(part1, stats1);
    k_Y  <<<NB * NI,            64,  0, stream>>>(V, W2, b2, Va, stats1, Y, part2);
    k_red<<<NB,                 256, 0, stream>>>(part2, stats2);
    k_out<<<(NB * NI * NC) / 256, 256, 0, stream>>>(Y, stats2, (float*)d_out);
}